// Round 1
// baseline (490.413 us; speedup 1.0000x reference)
//
#include <hip/hip_runtime.h>

// Problem constants (from reference).
#define N_GENOMES 30000
#define N_GENES   240000
#define N_SAMPLES 128
#define N_SEQS    80000

// One thread per (gene, quad-of-4-samples): 240000 * 32 threads.
// Coalesced float4 gather of A/B rows (genome_idx sorted -> high L1/L2 reuse),
// fused exp, scattered atomicAdd into the segment-sum output.
__global__ __launch_bounds__(256) void seg_exp_sum_kernel(
    const float* __restrict__ A,
    const float* __restrict__ B,
    const float* __restrict__ pos,
    const int*   __restrict__ genome_idx,
    const int*   __restrict__ seq_idx,
    float*       __restrict__ out)
{
    int idx  = blockIdx.x * blockDim.x + threadIdx.x;
    int gene = idx >> 5;          // 32 quads per gene (128 samples / 4)
    int quad = idx & 31;
    if (gene >= N_GENES) return;

    int   g = genome_idx[gene];   // wave-redundant scalar loads; L1 broadcast
    float p = pos[gene];
    int   s = seq_idx[gene];

    const float4 a = reinterpret_cast<const float4*>(A)[g * 32 + quad];
    const float4 b = reinterpret_cast<const float4*>(B)[g * 32 + quad];

    float4 e;
    e.x = __expf(a.x + 1.0f - p * b.x);
    e.y = __expf(a.y + 1.0f - p * b.y);
    e.z = __expf(a.z + 1.0f - p * b.z);
    e.w = __expf(a.w + 1.0f - p * b.w);

    float* o = out + (size_t)s * N_SAMPLES + quad * 4;
    atomicAdd(o + 0, e.x);
    atomicAdd(o + 1, e.y);
    atomicAdd(o + 2, e.z);
    atomicAdd(o + 3, e.w);
}

extern "C" void kernel_launch(void* const* d_in, const int* in_sizes, int n_in,
                              void* d_out, int out_size, void* d_ws, size_t ws_size,
                              hipStream_t stream) {
    const float* A    = (const float*)d_in[0];
    const float* B    = (const float*)d_in[1];
    const float* pos  = (const float*)d_in[2];
    const int*   gidx = (const int*)d_in[3];
    const int*   sidx = (const int*)d_in[4];
    float*       out  = (float*)d_out;

    // Harness poisons d_out with 0xAA before every launch; zero it (memset node
    // is graph-capture safe).
    hipMemsetAsync(out, 0, (size_t)out_size * sizeof(float), stream);

    const int total  = N_GENES * 32;              // 7,680,000 threads
    const int block  = 256;
    const int blocks = (total + block - 1) / block;
    seg_exp_sum_kernel<<<blocks, block, 0, stream>>>(A, B, pos, gidx, sidx, out);
}

// Round 2
// 143.020 us; speedup vs baseline: 3.4290x; 3.4290x over previous
//
#include <hip/hip_runtime.h>

// Problem constants (from reference).
#define N_GENOMES 30000
#define N_GENES   240000
#define N_SAMPLES 128
#define N_SEQS    80000
#define CAP       32   // max genes per seq bucket (Poisson mean = 3; P(overflow) ~ 3e-17)

// ---------------------------------------------------------------------------
// Kernel 1: bucket-scatter genes by sequence id.
//   cnt:    N_SEQS ints (zeroed before launch)
//   bucket: N_SEQS * CAP ints
// 240k atomics total (vs 30.7M in the naive version).
// ---------------------------------------------------------------------------
__global__ __launch_bounds__(256) void scatter_kernel(
    const int* __restrict__ seq_idx,
    int*       __restrict__ cnt,
    int*       __restrict__ bucket)
{
    int gene = blockIdx.x * blockDim.x + threadIdx.x;
    if (gene >= N_GENES) return;
    int s = seq_idx[gene];
    int slot = atomicAdd(&cnt[s], 1);
    if (slot < CAP) bucket[s * CAP + slot] = gene;
}

// ---------------------------------------------------------------------------
// Kernel 2: owner-computes segment sum.
// One thread per (seq, quad-of-4-samples): 80000 * 32 threads.
// Lanes 0..31 of a wave = 32 quads of one seq -> per-gene A/B loads are
// half-wave coalesced 512B row reads (served mostly from L2/L3: unique
// A+B = 30.7 MB). Register accumulation, one pure float4 store. No atomics.
// ---------------------------------------------------------------------------
__global__ __launch_bounds__(256) void accum_kernel(
    const float* __restrict__ A,
    const float* __restrict__ B,
    const float* __restrict__ pos,
    const int*   __restrict__ genome_idx,
    const int*   __restrict__ cnt,
    const int*   __restrict__ bucket,
    float*       __restrict__ out)
{
    int idx  = blockIdx.x * blockDim.x + threadIdx.x;
    int seq  = idx >> 5;
    int quad = idx & 31;
    if (seq >= N_SEQS) return;

    int n = cnt[seq];
    if (n > CAP) n = CAP;

    float4 acc = make_float4(0.f, 0.f, 0.f, 0.f);
    const int* bk = bucket + seq * CAP;

    for (int i = 0; i < n; ++i) {
        int   gene = bk[i];            // wave-redundant scalar loads; L1 broadcast
        int   g    = genome_idx[gene];
        float p    = pos[gene];

        const float4 a = reinterpret_cast<const float4*>(A)[g * 32 + quad];
        const float4 b = reinterpret_cast<const float4*>(B)[g * 32 + quad];

        acc.x += __expf(a.x + 1.0f - p * b.x);
        acc.y += __expf(a.y + 1.0f - p * b.y);
        acc.z += __expf(a.z + 1.0f - p * b.z);
        acc.w += __expf(a.w + 1.0f - p * b.w);
    }

    reinterpret_cast<float4*>(out)[seq * 32 + quad] = acc;
}

extern "C" void kernel_launch(void* const* d_in, const int* in_sizes, int n_in,
                              void* d_out, int out_size, void* d_ws, size_t ws_size,
                              hipStream_t stream) {
    const float* A    = (const float*)d_in[0];
    const float* B    = (const float*)d_in[1];
    const float* pos  = (const float*)d_in[2];
    const int*   gidx = (const int*)d_in[3];
    const int*   sidx = (const int*)d_in[4];
    float*       out  = (float*)d_out;

    // Workspace layout: [cnt: N_SEQS ints][bucket: N_SEQS*CAP ints]
    int* cnt    = (int*)d_ws;
    int* bucket = cnt + N_SEQS;

    // d_ws is re-poisoned 0xAA before every launch; zero the counters.
    hipMemsetAsync(cnt, 0, N_SEQS * sizeof(int), stream);

    scatter_kernel<<<(N_GENES + 255) / 256, 256, 0, stream>>>(sidx, cnt, bucket);

    const int total = N_SEQS * 32;   // 2,560,000 threads
    accum_kernel<<<(total + 255) / 256, 256, 0, stream>>>(
        A, B, pos, gidx, cnt, bucket, out);
}

// Round 3
// 132.419 us; speedup vs baseline: 3.7035x; 1.0801x over previous
//
#include <hip/hip_runtime.h>

// Problem constants (from reference).
#define N_GENOMES 30000
#define N_GENES   240000
#define N_SAMPLES 128
#define N_SEQS    80000
#define CAP       32   // max genes per seq bucket (Poisson mean = 3; P(overflow) ~ 3e-17)

// ---------------------------------------------------------------------------
// Kernel 1: bucket-scatter genes by sequence id, storing FAT records
// {genome_idx, pos} so the accumulate kernel skips the per-gene indirection.
//   cnt:    N_SEQS ints (zeroed before launch)
//   bucket: N_SEQS * CAP int2 records
// ---------------------------------------------------------------------------
__global__ __launch_bounds__(256) void scatter_kernel(
    const int*   __restrict__ seq_idx,
    const int*   __restrict__ genome_idx,
    const float* __restrict__ pos,
    int*         __restrict__ cnt,
    int2*        __restrict__ bucket)
{
    int gene = blockIdx.x * blockDim.x + threadIdx.x;
    if (gene >= N_GENES) return;
    int s = seq_idx[gene];
    int2 rec;
    rec.x = genome_idx[gene];          // coalesced (gene-ordered)
    rec.y = __float_as_int(pos[gene]); // coalesced
    int slot = atomicAdd(&cnt[s], 1);
    if (slot < CAP) bucket[s * CAP + slot] = rec;
}

// ---------------------------------------------------------------------------
// Kernel 2: owner-computes segment sum, chunk-of-4 software pipeline.
// One thread per (seq, quad-of-4-samples). Per chunk: 4 independent int2
// record loads -> 8 independent float4 row loads -> 4 exps, predicated
// accumulate. Dead slots read workspace poison; genome clamped to sentinel
// row 0 (L1-hot) so addresses stay valid, contribution masked out.
// ---------------------------------------------------------------------------
__global__ __launch_bounds__(256) void accum_kernel(
    const float* __restrict__ A,
    const float* __restrict__ B,
    const int*   __restrict__ cnt,
    const int2*  __restrict__ bucket,
    float*       __restrict__ out)
{
    int idx  = blockIdx.x * blockDim.x + threadIdx.x;
    int seq  = idx >> 5;
    int quad = idx & 31;
    if (seq >= N_SEQS) return;

    int n = cnt[seq];
    if (n > CAP) n = CAP;

    const int2* bk = bucket + seq * CAP;
    const float4* A4 = reinterpret_cast<const float4*>(A);
    const float4* B4 = reinterpret_cast<const float4*>(B);

    float4 acc = make_float4(0.f, 0.f, 0.f, 0.f);

    for (int i0 = 0; i0 < n; i0 += 4) {
        int2   r[4];
        int    g[4];
        float  p[4];
        bool   live[4];
        float4 a[4], b[4];

        #pragma unroll
        for (int j = 0; j < 4; ++j) {
            live[j] = (i0 + j) < n;
            r[j] = bk[i0 + j];               // always within CAP slots
        }
        #pragma unroll
        for (int j = 0; j < 4; ++j) {
            g[j] = live[j] ? r[j].x : 0;     // sentinel row 0 for dead slots
            p[j] = __int_as_float(r[j].y);
        }
        #pragma unroll
        for (int j = 0; j < 4; ++j) {        // 8 independent row loads in flight
            a[j] = A4[g[j] * 32 + quad];
            b[j] = B4[g[j] * 32 + quad];
        }
        #pragma unroll
        for (int j = 0; j < 4; ++j) {
            float4 e;
            e.x = __expf(a[j].x + 1.0f - p[j] * b[j].x);
            e.y = __expf(a[j].y + 1.0f - p[j] * b[j].y);
            e.z = __expf(a[j].z + 1.0f - p[j] * b[j].z);
            e.w = __expf(a[j].w + 1.0f - p[j] * b[j].w);
            if (live[j]) {
                acc.x += e.x; acc.y += e.y; acc.z += e.z; acc.w += e.w;
            }
        }
    }

    reinterpret_cast<float4*>(out)[seq * 32 + quad] = acc;
}

extern "C" void kernel_launch(void* const* d_in, const int* in_sizes, int n_in,
                              void* d_out, int out_size, void* d_ws, size_t ws_size,
                              hipStream_t stream) {
    const float* A    = (const float*)d_in[0];
    const float* B    = (const float*)d_in[1];
    const float* pos  = (const float*)d_in[2];
    const int*   gidx = (const int*)d_in[3];
    const int*   sidx = (const int*)d_in[4];
    float*       out  = (float*)d_out;

    // Workspace layout: [cnt: N_SEQS ints][bucket: N_SEQS*CAP int2]
    int*  cnt    = (int*)d_ws;
    int2* bucket = (int2*)(cnt + N_SEQS);

    // d_ws is re-poisoned 0xAA before every launch; zero the counters only.
    hipMemsetAsync(cnt, 0, N_SEQS * sizeof(int), stream);

    scatter_kernel<<<(N_GENES + 255) / 256, 256, 0, stream>>>(
        sidx, gidx, pos, cnt, bucket);

    const int total = N_SEQS * 32;   // 2,560,000 threads
    accum_kernel<<<(total + 255) / 256, 256, 0, stream>>>(
        A, B, cnt, bucket, out);
}